// Round 1
// baseline (329.672 us; speedup 1.0000x reference)
//
#include <hip/hip_runtime.h>
#include <hip/hip_bf16.h>

// Mapper: 4 per-word GEMM layers with LN+LeakyReLU between.
// bf16 MFMA GEMMs (fp32 accumulate), fp32 LN, bf16 activations.

typedef unsigned short u16;
typedef __attribute__((ext_vector_type(8))) short bf16x8;
typedef __attribute__((ext_vector_type(4))) float f32x4;

constexpr int CB = 256;      // batch
constexpr int CW = 20;       // words
constexpr int CDIN = 1024;
constexpr int CDOUT = 1024;
constexpr int CH = 1280;
constexpr float CEPS = 1e-5f;
constexpr float CSLOPE = 0.01f;

// fp32 -> bf16 round-to-nearest-even
__device__ __forceinline__ u16 f2bf(float f) {
    union { float f; unsigned u; } v; v.f = f;
    unsigned r = v.u + 0x7fffu + ((v.u >> 16) & 1u);
    return (u16)(r >> 16);
}
__device__ __forceinline__ unsigned pk2(float a, float b) {
    return (unsigned)f2bf(a) | ((unsigned)f2bf(b) << 16);
}

// ---------------------------------------------------------------------------
// GEMM: out[b, w, n] = sum_k A[b, w, k] * Bw[w, k, n] + bias[w, n]
// A: bf16 (u16), row (b*CW+w), K-contiguous.  Bw: fp32 [W][K][N].  Out: fp32.
// Tile: BM=128 (over b), BN=128 (over n), BK=32. 256 threads = 4 waves (2x2),
// each wave a 64x64 subtile = 4x4 MFMA 16x16x32 tiles.
// LDS: A and B tiles stored K-contiguous with row stride 40 (pad 8) bf16.
// ---------------------------------------------------------------------------
template <int K, int N>
__global__ __launch_bounds__(256, 2) void gemm_kernel(
    const u16* __restrict__ Ab, const float* __restrict__ Bw,
    const float* __restrict__ bias, float* __restrict__ Out)
{
    constexpr int NB = N / 128;
    constexpr int NK = K / 32;
    __shared__ u16 As[2][128 * 40];
    __shared__ u16 Bs[2][128 * 40];

    const int t   = threadIdx.x;
    const int bid = blockIdx.x;
    const int mb  = bid & 1;
    const int nb  = (bid >> 1) % NB;
    const int w   = bid / (2 * NB);

    const int m0g = mb * 128;
    const int n0g = nb * 128;

    const int lane = t & 63;
    const int wid  = t >> 6;
    const int m0 = (wid >> 1) * 64;
    const int n0 = (wid & 1) * 64;
    const int lrow = lane & 15;
    const int kg   = lane >> 4;           // 0..3, k-chunk of 8

    // A staging: thread -> (row = t>>1, k-quarter = (t&1)*16), 16 bf16 = 2x16B
    const int ar  = t >> 1;
    const int akq = (t & 1) << 4;
    const u16* agp = Ab + ((size_t)(m0g + ar) * CW + w) * K + akq;

    // B staging: thread -> (n = t&127, k-half = t>>7), 16 fp32 dwords along k
    const int bn = t & 127;
    const int bh = t >> 7;
    const float* bgp = Bw + (size_t)w * K * N + (size_t)bh * 16 * N + (n0g + bn);

    f32x4 acc[4][4];
    #pragma unroll
    for (int i = 0; i < 4; ++i)
        #pragma unroll
        for (int j = 0; j < 4; ++j)
            acc[i][j] = (f32x4){0.f, 0.f, 0.f, 0.f};

    uint4 a0, a1;
    float bstg[16];

    auto loadA = [&](int k0) {
        const uint4* p = reinterpret_cast<const uint4*>(agp + k0);
        a0 = p[0]; a1 = p[1];
    };
    auto loadB = [&](int k0) {
        const float* p = bgp + (size_t)k0 * N;
        #pragma unroll
        for (int i = 0; i < 16; ++i) bstg[i] = p[(size_t)i * N];
    };
    auto writeA = [&](int buf) {
        *reinterpret_cast<uint4*>(&As[buf][ar * 40 + akq])     = a0;
        *reinterpret_cast<uint4*>(&As[buf][ar * 40 + akq + 8]) = a1;
    };
    auto writeB = [&](int buf) {
        uint4 p0, p1;
        p0.x = pk2(bstg[0],  bstg[1]);  p0.y = pk2(bstg[2],  bstg[3]);
        p0.z = pk2(bstg[4],  bstg[5]);  p0.w = pk2(bstg[6],  bstg[7]);
        p1.x = pk2(bstg[8],  bstg[9]);  p1.y = pk2(bstg[10], bstg[11]);
        p1.z = pk2(bstg[12], bstg[13]); p1.w = pk2(bstg[14], bstg[15]);
        *reinterpret_cast<uint4*>(&Bs[buf][bn * 40 + bh * 16])     = p0;
        *reinterpret_cast<uint4*>(&Bs[buf][bn * 40 + bh * 16 + 8]) = p1;
    };
    auto compute = [&](int buf) {
        bf16x8 af[4], bfr[4];
        #pragma unroll
        for (int i = 0; i < 4; ++i)
            af[i] = *reinterpret_cast<const bf16x8*>(
                &As[buf][(m0 + i * 16 + lrow) * 40 + kg * 8]);
        #pragma unroll
        for (int j = 0; j < 4; ++j)
            bfr[j] = *reinterpret_cast<const bf16x8*>(
                &Bs[buf][(n0 + j * 16 + lrow) * 40 + kg * 8]);
        #pragma unroll
        for (int i = 0; i < 4; ++i)
            #pragma unroll
            for (int j = 0; j < 4; ++j)
                acc[i][j] = __builtin_amdgcn_mfma_f32_16x16x32_bf16(
                    af[i], bfr[j], acc[i][j], 0, 0, 0);
    };

    loadA(0); loadB(0);
    writeA(0); writeB(0);
    __syncthreads();

    int buf = 0;
    for (int ks = 0; ks < NK; ++ks) {
        if (ks + 1 < NK) { loadA((ks + 1) * 32); loadB((ks + 1) * 32); }
        compute(buf);
        if (ks + 1 < NK) { writeA(buf ^ 1); writeB(buf ^ 1); }
        __syncthreads();
        buf ^= 1;
    }

    // epilogue: + bias, store fp32
    const int rb = (lane >> 4) * 4;
    #pragma unroll
    for (int j = 0; j < 4; ++j) {
        const int gn = n0g + n0 + j * 16 + lrow;
        const float bv = bias[(size_t)w * N + gn];
        #pragma unroll
        for (int i = 0; i < 4; ++i) {
            const int gm = m0g + m0 + i * 16 + rb;
            #pragma unroll
            for (int r = 0; r < 4; ++r) {
                Out[((size_t)(gm + r) * CW + w) * N + gn] = acc[i][j][r] + bv;
            }
        }
    }
}

// ---------------------------------------------------------------------------
// LayerNorm + LeakyReLU over last dim (H=1280), writes bf16.
// One block (320 threads, 5 waves) per row; each thread one float4.
// ---------------------------------------------------------------------------
__global__ __launch_bounds__(320) void ln_lrelu_kernel(
    const float* __restrict__ h, const float* __restrict__ g,
    const float* __restrict__ bta, u16* __restrict__ out)
{
    const int row = blockIdx.x;          // b*CW + w
    const int w = row % CW;
    const int t = threadIdx.x;

    const float4 v = reinterpret_cast<const float4*>(h + (size_t)row * CH)[t];
    float s  = v.x + v.y + v.z + v.w;
    float sq = v.x * v.x + v.y * v.y + v.z * v.z + v.w * v.w;
    #pragma unroll
    for (int o = 32; o > 0; o >>= 1) {
        s  += __shfl_down(s, o, 64);
        sq += __shfl_down(sq, o, 64);
    }
    __shared__ float ss[5], sg[5];
    const int lane = t & 63, wv = t >> 6;
    if (lane == 0) { ss[wv] = s; sg[wv] = sq; }
    __syncthreads();
    float S = 0.f, Q = 0.f;
    #pragma unroll
    for (int i = 0; i < 5; ++i) { S += ss[i]; Q += sg[i]; }
    const float mean = S * (1.0f / CH);
    const float var  = Q * (1.0f / CH) - mean * mean;
    const float rstd = rsqrtf(var + CEPS);

    const float4 gg = reinterpret_cast<const float4*>(g   + (size_t)w * CH)[t];
    const float4 bb = reinterpret_cast<const float4*>(bta + (size_t)w * CH)[t];
    float4 y;
    y.x = (v.x - mean) * rstd * gg.x + bb.x;
    y.y = (v.y - mean) * rstd * gg.y + bb.y;
    y.z = (v.z - mean) * rstd * gg.z + bb.z;
    y.w = (v.w - mean) * rstd * gg.w + bb.w;
    y.x = y.x >= 0.f ? y.x : CSLOPE * y.x;
    y.y = y.y >= 0.f ? y.y : CSLOPE * y.y;
    y.z = y.z >= 0.f ? y.z : CSLOPE * y.z;
    y.w = y.w >= 0.f ? y.w : CSLOPE * y.w;
    ushort4 o4;
    o4.x = f2bf(y.x); o4.y = f2bf(y.y); o4.z = f2bf(y.z); o4.w = f2bf(y.w);
    reinterpret_cast<ushort4*>(out + (size_t)row * CH)[t] = o4;
}

// fp32 -> bf16 elementwise (for embs)
__global__ void cvt_kernel(const float* __restrict__ in, u16* __restrict__ out,
                           int n4)
{
    const int i = blockIdx.x * blockDim.x + threadIdx.x;
    if (i < n4) {
        const float4 v = reinterpret_cast<const float4*>(in)[i];
        ushort4 o;
        o.x = f2bf(v.x); o.y = f2bf(v.y); o.z = f2bf(v.z); o.w = f2bf(v.w);
        reinterpret_cast<ushort4*>(out)[i] = o;
    }
}

extern "C" void kernel_launch(void* const* d_in, const int* in_sizes, int n_in,
                              void* d_out, int out_size, void* d_ws, size_t ws_size,
                              hipStream_t stream)
{
    const float* embs = (const float*)d_in[0];
    const float* W1  = (const float*)d_in[1];
    const float* b1  = (const float*)d_in[2];
    const float* g1  = (const float*)d_in[3];
    const float* bn1 = (const float*)d_in[4];
    const float* W2  = (const float*)d_in[5];
    const float* b2  = (const float*)d_in[6];
    const float* g2  = (const float*)d_in[7];
    const float* bn2 = (const float*)d_in[8];
    const float* W3  = (const float*)d_in[9];
    const float* b3  = (const float*)d_in[10];
    const float* g3  = (const float*)d_in[11];
    const float* bn3 = (const float*)d_in[12];
    const float* W4  = (const float*)d_in[13];
    const float* b4  = (const float*)d_in[14];

    char* ws = (char*)d_ws;
    float* h_raw = (float*)ws;                               // B*W*H*4  = 26,214,400
    u16*   a_bf  = (u16*)(ws + 26214400);                    // B*W*H*2  = 13,107,200
    u16*   e_bf  = (u16*)(ws + 26214400 + 13107200);         // B*W*DIN*2 = 10,485,760

    const int n4 = CB * CW * CDIN / 4;                       // 1,310,720
    cvt_kernel<<<n4 / 256, 256, 0, stream>>>(embs, e_bf, n4);

    // Layer 1: [256x1024] @ [1024x1280]
    gemm_kernel<CDIN, CH><<<CW * 2 * (CH / 128), 256, 0, stream>>>(e_bf, W1, b1, h_raw);
    ln_lrelu_kernel<<<CB * CW, 320, 0, stream>>>(h_raw, g1, bn1, a_bf);
    // Layer 2: [256x1280] @ [1280x1280]
    gemm_kernel<CH, CH><<<CW * 2 * (CH / 128), 256, 0, stream>>>(a_bf, W2, b2, h_raw);
    ln_lrelu_kernel<<<CB * CW, 320, 0, stream>>>(h_raw, g2, bn2, a_bf);
    // Layer 3: [256x1280] @ [1280x1280]
    gemm_kernel<CH, CH><<<CW * 2 * (CH / 128), 256, 0, stream>>>(a_bf, W3, b3, h_raw);
    ln_lrelu_kernel<<<CB * CW, 320, 0, stream>>>(h_raw, g3, bn3, a_bf);
    // Layer 4: [256x1280] @ [1280x1024] -> d_out (fp32)
    gemm_kernel<CH, CDOUT><<<CW * 2 * (CDOUT / 128), 256, 0, stream>>>(a_bf, W4, b4, (float*)d_out);
}